// Round 2
// baseline (873.724 us; speedup 1.0000x reference)
//
#include <hip/hip_runtime.h>

// GCN encoder: 3x (GCNConv + ReLU), dims 256->128->64->32
// N=50000 nodes, E=800000 edges, fp32. edge_index delivered as int32 (harness).

#define D0 256
#define D1 128
#define D2 64
#define D3 32

// ---------------------------------------------------------------- degree ----
__global__ void deg_kernel(const int* __restrict__ ei, const float* __restrict__ ew,
                           float* __restrict__ deg, int E) {
    int e = blockIdx.x * blockDim.x + threadIdx.x;
    if (e < E) {
        int c = ei[E + e];   // col (target)
        atomicAdd(&deg[c], ew[e]);
    }
}

__global__ void dinv_kernel(float* __restrict__ deg_dinv, int N) {
    int i = blockIdx.x * blockDim.x + threadIdx.x;
    if (i < N) {
        float d = deg_dinv[i] + 1.0f;   // +1 for the self-loop weight
        deg_dinv[i] = (d > 0.0f) ? rsqrtf(d) : 0.0f;
    }
}

__global__ void norm_kernel(const int* __restrict__ ei, const float* __restrict__ ew,
                            const float* __restrict__ dinv, float* __restrict__ norm, int E) {
    int e = blockIdx.x * blockDim.x + threadIdx.x;
    if (e < E) {
        int r = ei[e];
        int c = ei[E + e];
        norm[e] = dinv[r] * ew[e] * dinv[c];
    }
}

// ------------------------------------------------------------------ GEMM ----
// H[N,DOUT] = X[N,K] @ W[K,DOUT].  BM=64 rows/block, BK=16, 256 threads
// (16x16), each thread computes a 4xTN micro-tile. BN = columns per block.
template <int K, int DOUT, int BN, int TN>
__global__ __launch_bounds__(256) void gemm_kernel(const float* __restrict__ X,
                                                   const float* __restrict__ W,
                                                   float* __restrict__ H, int N) {
    constexpr int BM = 64, BK = 16;
    __shared__ float As[BK][BM];   // x tile, transposed: As[k][m]
    __shared__ float Bs[BK][BN];   // W tile: Bs[k][n]

    const int tid = threadIdx.x;
    const int tx = tid & 15;    // col group 0..15
    const int ty = tid >> 4;    // row group 0..15
    const int row0 = blockIdx.x * BM;
    const int n0 = blockIdx.y * BN;

    float acc[4][TN];
#pragma unroll
    for (int i = 0; i < 4; ++i)
#pragma unroll
        for (int j = 0; j < TN; ++j) acc[i][j] = 0.0f;

    for (int k0 = 0; k0 < K; k0 += BK) {
        // --- stage X tile: 64 rows x 16 k  (1024 floats, 1 float4/thread)
        {
            int m = tid >> 2;            // 0..63
            int kq = (tid & 3) << 2;     // 0,4,8,12
            int r = row0 + m;
            float4 v = make_float4(0.f, 0.f, 0.f, 0.f);
            if (r < N) v = *(const float4*)&X[(size_t)r * K + k0 + kq];
            As[kq + 0][m] = v.x;
            As[kq + 1][m] = v.y;
            As[kq + 2][m] = v.z;
            As[kq + 3][m] = v.w;
        }
        // --- stage W tile: 16 k x BN cols
        if constexpr (BN == 64) {
            int k = tid >> 4;             // 0..15
            int nq = (tid & 15) << 2;     // 0..60
            float4 v = *(const float4*)&W[(size_t)(k0 + k) * DOUT + n0 + nq];
            *(float4*)&Bs[k][nq] = v;
        } else {  // BN == 32: 512 floats, 2/thread
            int idx = tid * 2;
            int k = idx >> 5;             // 0..15
            int nq = idx & 31;
            float2 v = *(const float2*)&W[(size_t)(k0 + k) * DOUT + n0 + nq];
            Bs[k][nq] = v.x;
            Bs[k][nq + 1] = v.y;
        }
        __syncthreads();

#pragma unroll
        for (int k = 0; k < BK; ++k) {
            float a[4];
            *(float4*)a = *(const float4*)&As[k][ty * 4];
            float b[TN];
            if constexpr (TN == 4) {
                *(float4*)b = *(const float4*)&Bs[k][tx * 4];
            } else {
                float2 t2 = *(const float2*)&Bs[k][tx * 2];
                b[0] = t2.x; b[1] = t2.y;
            }
#pragma unroll
            for (int i = 0; i < 4; ++i)
#pragma unroll
                for (int j = 0; j < TN; ++j) acc[i][j] = fmaf(a[i], b[j], acc[i][j]);
        }
        __syncthreads();
    }

#pragma unroll
    for (int i = 0; i < 4; ++i) {
        int r = row0 + ty * 4 + i;
        if (r < N) {
            float* dst = &H[(size_t)r * DOUT + n0 + tx * TN];
            if constexpr (TN == 4) {
                float4 v = make_float4(acc[i][0], acc[i][1], acc[i][2], acc[i][3]);
                *(float4*)dst = v;
            } else {
                float2 v = make_float2(acc[i][0], acc[i][1]);
                *(float2*)dst = v;
            }
        }
    }
}

// --------------------------------------------------------------- scatter ----
// One thread per (edge, channel): agg[col][j] += h[row][j] * norm[e]
template <int DOUT, int LOG>
__global__ void scatter_kernel(const float* __restrict__ H, const int* __restrict__ ei,
                               const float* __restrict__ norm, float* __restrict__ agg, int E) {
    long long gid = (long long)blockIdx.x * blockDim.x + threadIdx.x;
    int e = (int)(gid >> LOG);
    int j = (int)(gid & (DOUT - 1));
    if (e >= E) return;
    int r = ei[e];
    int c = ei[E + e];
    float v = H[(size_t)r * DOUT + j] * norm[e];
    atomicAdd(&agg[(size_t)c * DOUT + j], v);
}

// -------------------------------------------------------------- finalize ----
// out = relu(agg + dinv[i]^2 * h[i]  (self-loop)  + bias)
template <int DOUT, int LOG>
__global__ void finalize_kernel(const float* __restrict__ agg, const float* __restrict__ H,
                                const float* __restrict__ dinv, const float* __restrict__ bias,
                                float* __restrict__ out, int N) {
    int gid = blockIdx.x * blockDim.x + threadIdx.x;
    if (gid >= N * DOUT) return;
    int i = gid >> LOG;
    int j = gid & (DOUT - 1);
    float di = dinv[i];
    float v = agg[gid] + di * di * H[gid] + bias[j];
    out[gid] = fmaxf(v, 0.0f);
}

// ---------------------------------------------------------------- launch ----
extern "C" void kernel_launch(void* const* d_in, const int* in_sizes, int n_in,
                              void* d_out, int out_size, void* d_ws, size_t ws_size,
                              hipStream_t stream) {
    const float* x   = (const float*)d_in[0];
    const int* ei    = (const int*)d_in[1];      // int32 on device (harness converts)
    const float* ew  = (const float*)d_in[2];
    const float* W1  = (const float*)d_in[3];
    const float* b1  = (const float*)d_in[4];
    const float* W2  = (const float*)d_in[5];
    const float* b2  = (const float*)d_in[6];
    const float* W3  = (const float*)d_in[7];
    const float* b3  = (const float*)d_in[8];
    float* out = (float*)d_out;

    const int N = in_sizes[0] / D0;   // 50000
    const int E = in_sizes[2];        // 800000
    (void)n_in; (void)out_size; (void)ws_size;

    // ---- workspace carving (all 256B aligned) ----
    char* ws = (char*)d_ws;
    size_t off = 0;
    auto carve = [&](size_t bytes) -> float* {
        float* p = (float*)(ws + off);
        off += (bytes + 255) & ~(size_t)255;
        return p;
    };
    float* dinv = carve((size_t)N * 4);            // deg then dinv, in place
    float* norm = carve((size_t)E * 4);
    float* bufA = carve((size_t)N * D1 * 4);       // 25.6 MB
    float* bufB = carve((size_t)N * D1 * 4);       // 25.6 MB

    float* h1   = bufA;                 // N x 128
    float* agg1 = bufB;                 // N x 128 ; becomes x for layer 2
    float* h2   = bufA;                 // N x 64  (bufA lower half)
    float* agg2 = bufA + (size_t)N * D2;// N x 64  (bufA upper half) ; x for layer 3
    float* h3   = bufB;                 // N x 32  (bufB free after L2 gemm)
    float* agg3 = out;                  // N x 32  aggregated directly in d_out

    const int eb = (E + 255) / 256;
    const int nb = (N + 255) / 256;
    const int rowBlocks = (N + 63) / 64;

    // ---- normalization coefficients ----
    hipMemsetAsync(dinv, 0, (size_t)N * 4, stream);
    deg_kernel<<<eb, 256, 0, stream>>>(ei, ew, dinv, E);
    dinv_kernel<<<nb, 256, 0, stream>>>(dinv, N);
    norm_kernel<<<eb, 256, 0, stream>>>(ei, ew, dinv, norm, E);

    // ---- layer 1: 256 -> 128 ----
    gemm_kernel<D0, D1, 64, 4><<<dim3(rowBlocks, 2), 256, 0, stream>>>(x, W1, h1, N);
    hipMemsetAsync(agg1, 0, (size_t)N * D1 * 4, stream);
    {
        long long total = (long long)E << 7;
        scatter_kernel<D1, 7><<<(int)((total + 255) / 256), 256, 0, stream>>>(h1, ei, norm, agg1, E);
        finalize_kernel<D1, 7><<<(N * D1 + 255) / 256, 256, 0, stream>>>(agg1, h1, dinv, b1, agg1, N);
    }

    // ---- layer 2: 128 -> 64 ----
    gemm_kernel<D1, D2, 64, 4><<<dim3(rowBlocks, 1), 256, 0, stream>>>(agg1, W2, h2, N);
    hipMemsetAsync(agg2, 0, (size_t)N * D2 * 4, stream);
    {
        long long total = (long long)E << 6;
        scatter_kernel<D2, 6><<<(int)((total + 255) / 256), 256, 0, stream>>>(h2, ei, norm, agg2, E);
        finalize_kernel<D2, 6><<<(N * D2 + 255) / 256, 256, 0, stream>>>(agg2, h2, dinv, b2, agg2, N);
    }

    // ---- layer 3: 64 -> 32 ----
    gemm_kernel<D2, D3, 32, 2><<<dim3(rowBlocks, 1), 256, 0, stream>>>(agg2, W3, h3, N);
    hipMemsetAsync(agg3, 0, (size_t)N * D3 * 4, stream);
    {
        long long total = (long long)E << 5;
        scatter_kernel<D3, 5><<<(int)((total + 255) / 256), 256, 0, stream>>>(h3, ei, norm, agg3, E);
        finalize_kernel<D3, 5><<<(N * D3 + 255) / 256, 256, 0, stream>>>(agg3, h3, dinv, b3, out, N);
    }
}

// Round 3
// 534.915 us; speedup vs baseline: 1.6334x; 1.6334x over previous
//
#include <hip/hip_runtime.h>

// GCN encoder: 3x (GCNConv + ReLU), dims 256->128->64->32
// N=50000 nodes, E=800000 edges, fp32. edge_index delivered as int32 (harness).
// R2: replace atomic scatter (400MB write-through per layer) with CSR gather.

#define D0 256
#define D1 128
#define D2 64
#define D3 32

// ------------------------------------------------- degree + histogram ------
__global__ void deg_hist_kernel(const int* __restrict__ ei, const float* __restrict__ ew,
                                float* __restrict__ deg, int* __restrict__ cnt, int E) {
    int e = blockIdx.x * blockDim.x + threadIdx.x;
    if (e < E) {
        int c = ei[E + e];   // col (target)
        atomicAdd(&deg[c], ew[e]);
        atomicAdd(&cnt[c], 1);
    }
}

__global__ void dinv_kernel(float* __restrict__ deg_dinv, int N) {
    int i = blockIdx.x * blockDim.x + threadIdx.x;
    if (i < N) {
        float d = deg_dinv[i] + 1.0f;   // +1 for the self-loop weight
        deg_dinv[i] = (d > 0.0f) ? rsqrtf(d) : 0.0f;
    }
}

// ------------------------------------------------- single-block scan -------
// Exclusive prefix sum of cnt[0..N) -> row_ptr[0..N], plus cursor copy.
__global__ __launch_bounds__(1024) void scan_kernel(const int* __restrict__ cnt,
                                                    int* __restrict__ row_ptr,
                                                    int* __restrict__ cursor, int N) {
    __shared__ int part[1024];
    const int t = threadIdx.x;
    const int C = (N + 1023) >> 10;
    const int lo = t * C;
    const int hi = min(lo + C, N);
    int s = 0;
    for (int i = lo; i < hi; ++i) s += cnt[i];
    part[t] = s;
    __syncthreads();
    // inclusive Hillis-Steele scan over 1024 partials
    for (int off = 1; off < 1024; off <<= 1) {
        int v = part[t];
        int u = (t >= off) ? part[t - off] : 0;
        __syncthreads();
        part[t] = v + u;
        __syncthreads();
    }
    int run = part[t] - s;   // exclusive base for this chunk
    for (int i = lo; i < hi; ++i) {
        row_ptr[i] = run;
        cursor[i] = run;
        run += cnt[i];
    }
    if (t == 1023) row_ptr[N] = part[1023];
}

// ------------------------------------------------- bucket fill (CSR) -------
// Sort edges by destination; compute norm on the fly.
__global__ void fill_kernel(const int* __restrict__ ei, const float* __restrict__ ew,
                            const float* __restrict__ dinv, int* __restrict__ cursor,
                            int* __restrict__ src_s, float* __restrict__ nrm_s, int E) {
    int e = blockIdx.x * blockDim.x + threadIdx.x;
    if (e < E) {
        int r = ei[e];
        int c = ei[E + e];
        float w = dinv[r] * ew[e] * dinv[c];
        int pos = atomicAdd(&cursor[c], 1);
        src_s[pos] = r;
        nrm_s[pos] = w;
    }
}

// ------------------------------------------------------------------ GEMM ----
// H[N,DOUT] = X[N,K] @ W[K,DOUT].  BM=64 rows/block, BK=16, 256 threads
// (16x16), each thread computes a 4xTN micro-tile. BN = columns per block.
template <int K, int DOUT, int BN, int TN>
__global__ __launch_bounds__(256) void gemm_kernel(const float* __restrict__ X,
                                                   const float* __restrict__ W,
                                                   float* __restrict__ H, int N) {
    constexpr int BM = 64, BK = 16;
    __shared__ float As[BK][BM];   // x tile, transposed: As[k][m]
    __shared__ float Bs[BK][BN];   // W tile: Bs[k][n]

    const int tid = threadIdx.x;
    const int tx = tid & 15;    // col group 0..15
    const int ty = tid >> 4;    // row group 0..15
    const int row0 = blockIdx.x * BM;
    const int n0 = blockIdx.y * BN;

    float acc[4][TN];
#pragma unroll
    for (int i = 0; i < 4; ++i)
#pragma unroll
        for (int j = 0; j < TN; ++j) acc[i][j] = 0.0f;

    for (int k0 = 0; k0 < K; k0 += BK) {
        {
            int m = tid >> 2;            // 0..63
            int kq = (tid & 3) << 2;     // 0,4,8,12
            int r = row0 + m;
            float4 v = make_float4(0.f, 0.f, 0.f, 0.f);
            if (r < N) v = *(const float4*)&X[(size_t)r * K + k0 + kq];
            As[kq + 0][m] = v.x;
            As[kq + 1][m] = v.y;
            As[kq + 2][m] = v.z;
            As[kq + 3][m] = v.w;
        }
        if constexpr (BN == 64) {
            int k = tid >> 4;             // 0..15
            int nq = (tid & 15) << 2;     // 0..60
            float4 v = *(const float4*)&W[(size_t)(k0 + k) * DOUT + n0 + nq];
            *(float4*)&Bs[k][nq] = v;
        } else {  // BN == 32
            int idx = tid * 2;
            int k = idx >> 5;
            int nq = idx & 31;
            float2 v = *(const float2*)&W[(size_t)(k0 + k) * DOUT + n0 + nq];
            Bs[k][nq] = v.x;
            Bs[k][nq + 1] = v.y;
        }
        __syncthreads();

#pragma unroll
        for (int k = 0; k < BK; ++k) {
            float a[4];
            *(float4*)a = *(const float4*)&As[k][ty * 4];
            float b[TN];
            if constexpr (TN == 4) {
                *(float4*)b = *(const float4*)&Bs[k][tx * 4];
            } else {
                float2 t2 = *(const float2*)&Bs[k][tx * 2];
                b[0] = t2.x; b[1] = t2.y;
            }
#pragma unroll
            for (int i = 0; i < 4; ++i)
#pragma unroll
                for (int j = 0; j < TN; ++j) acc[i][j] = fmaf(a[i], b[j], acc[i][j]);
        }
        __syncthreads();
    }

#pragma unroll
    for (int i = 0; i < 4; ++i) {
        int r = row0 + ty * 4 + i;
        if (r < N) {
            float* dst = &H[(size_t)r * DOUT + n0 + tx * TN];
            if constexpr (TN == 4) {
                *(float4*)dst = make_float4(acc[i][0], acc[i][1], acc[i][2], acc[i][3]);
            } else {
                *(float2*)dst = make_float2(acc[i][0], acc[i][1]);
            }
        }
    }
}

// -------------------------------------------- fused aggregate + epilogue ----
// out[c][:] = relu( sum_{e in in(c)} nrm[e]*H[src[e]][:] + dinv[c]^2*H[c][:] + b )
// D/4 lanes per node (float4), 256 threads/block.
template <int D>
__global__ __launch_bounds__(256) void agg_kernel(const float* __restrict__ H,
                                                  const int* __restrict__ row_ptr,
                                                  const int* __restrict__ src_s,
                                                  const float* __restrict__ nrm_s,
                                                  const float* __restrict__ dinv,
                                                  const float* __restrict__ bias,
                                                  float* __restrict__ out, int N) {
    constexpr int TPN = D / 4;        // threads per node
    constexpr int NPB = 256 / TPN;    // nodes per block
    const int tid = threadIdx.x;
    const int g = tid / TPN;
    const int lane = tid % TPN;
    const int node = blockIdx.x * NPB + g;
    if (node >= N) return;

    const int beg = row_ptr[node];
    const int end = row_ptr[node + 1];
    float4 acc = make_float4(0.f, 0.f, 0.f, 0.f);
    for (int k = beg; k < end; ++k) {
        int s = src_s[k];
        float w = nrm_s[k];
        float4 h = *(const float4*)&H[(size_t)s * D + lane * 4];
        acc.x = fmaf(w, h.x, acc.x);
        acc.y = fmaf(w, h.y, acc.y);
        acc.z = fmaf(w, h.z, acc.z);
        acc.w = fmaf(w, h.w, acc.w);
    }
    // self-loop + bias + relu
    float di = dinv[node];
    float d2 = di * di;
    float4 hd = *(const float4*)&H[(size_t)node * D + lane * 4];
    acc.x = fmaf(d2, hd.x, acc.x);
    acc.y = fmaf(d2, hd.y, acc.y);
    acc.z = fmaf(d2, hd.z, acc.z);
    acc.w = fmaf(d2, hd.w, acc.w);
    float4 b = *(const float4*)&bias[lane * 4];
    acc.x = fmaxf(acc.x + b.x, 0.f);
    acc.y = fmaxf(acc.y + b.y, 0.f);
    acc.z = fmaxf(acc.z + b.z, 0.f);
    acc.w = fmaxf(acc.w + b.w, 0.f);
    *(float4*)&out[(size_t)node * D + lane * 4] = acc;
}

// ---------------------------------------------------------------- launch ----
extern "C" void kernel_launch(void* const* d_in, const int* in_sizes, int n_in,
                              void* d_out, int out_size, void* d_ws, size_t ws_size,
                              hipStream_t stream) {
    const float* x   = (const float*)d_in[0];
    const int* ei    = (const int*)d_in[1];
    const float* ew  = (const float*)d_in[2];
    const float* W1  = (const float*)d_in[3];
    const float* b1  = (const float*)d_in[4];
    const float* W2  = (const float*)d_in[5];
    const float* b2  = (const float*)d_in[6];
    const float* W3  = (const float*)d_in[7];
    const float* b3  = (const float*)d_in[8];
    float* out = (float*)d_out;

    const int N = in_sizes[0] / D0;   // 50000
    const int E = in_sizes[2];        // 800000
    (void)n_in; (void)out_size; (void)ws_size;

    // ---- workspace carving ----
    char* ws = (char*)d_ws;
    size_t off = 0;
    auto carve = [&](size_t bytes) -> void* {
        void* p = (void*)(ws + off);
        off += (bytes + 255) & ~(size_t)255;
        return p;
    };
    float* dinv    = (float*)carve((size_t)N * 4);
    int*   cnt     = (int*)carve((size_t)N * 4);
    int*   row_ptr = (int*)carve((size_t)(N + 1) * 4);
    int*   cursor  = (int*)carve((size_t)N * 4);
    int*   src_s   = (int*)carve((size_t)E * 4);
    float* nrm_s   = (float*)carve((size_t)E * 4);
    float* bufA    = (float*)carve((size_t)N * D1 * 4);   // 25.6 MB
    float* bufB    = (float*)carve((size_t)N * D1 * 4);   // 25.6 MB

    float* h1   = bufA;                  // N x 128
    float* out1 = bufB;                  // N x 128 ; x for layer 2
    float* h2   = bufA;                  // N x 64
    float* out2 = bufA + (size_t)N * D2; // N x 64 ; x for layer 3
    float* h3   = bufB;                  // N x 32

    const int eb = (E + 255) / 256;
    const int nb = (N + 255) / 256;
    const int rowBlocks = (N + 63) / 64;

    // ---- CSR build + normalization ----
    hipMemsetAsync(dinv, 0, (size_t)N * 4, stream);
    hipMemsetAsync(cnt, 0, (size_t)N * 4, stream);
    deg_hist_kernel<<<eb, 256, 0, stream>>>(ei, ew, dinv, cnt, E);
    dinv_kernel<<<nb, 256, 0, stream>>>(dinv, N);
    scan_kernel<<<1, 1024, 0, stream>>>(cnt, row_ptr, cursor, N);
    fill_kernel<<<eb, 256, 0, stream>>>(ei, ew, dinv, cursor, src_s, nrm_s, E);

    // ---- layer 1: 256 -> 128 ----
    gemm_kernel<D0, D1, 64, 4><<<dim3(rowBlocks, 2), 256, 0, stream>>>(x, W1, h1, N);
    agg_kernel<D1><<<(N + 7) / 8, 256, 0, stream>>>(h1, row_ptr, src_s, nrm_s, dinv, b1, out1, N);

    // ---- layer 2: 128 -> 64 ----
    gemm_kernel<D1, D2, 64, 4><<<dim3(rowBlocks, 1), 256, 0, stream>>>(out1, W2, h2, N);
    agg_kernel<D2><<<(N + 15) / 16, 256, 0, stream>>>(h2, row_ptr, src_s, nrm_s, dinv, b2, out2, N);

    // ---- layer 3: 64 -> 32 ----
    gemm_kernel<D2, D3, 32, 2><<<dim3(rowBlocks, 1), 256, 0, stream>>>(out2, W3, h3, N);
    agg_kernel<D3><<<(N + 31) / 32, 256, 0, stream>>>(h3, row_ptr, src_s, nrm_s, dinv, b3, out, N);
}

// Round 4
// 436.818 us; speedup vs baseline: 2.0002x; 1.2246x over previous
//
#include <hip/hip_runtime.h>

// GCN encoder: 3x (GCNConv + ReLU), dims 256->128->64->32
// N=50000 nodes, E=800000 edges, fp32. edge_index delivered as int32 (harness).
// R2: CSR gather instead of atomic scatter.
// R3: multi-block 3-phase scan (old single-block scan was 112us on 1 CU).

#define D0 256
#define D1 128
#define D2 64
#define D3 32

// ------------------------------------------------- degree + histogram ------
__global__ void deg_hist_kernel(const int* __restrict__ ei, const float* __restrict__ ew,
                                float* __restrict__ deg, int* __restrict__ cnt, int E) {
    int e = blockIdx.x * blockDim.x + threadIdx.x;
    if (e < E) {
        int c = ei[E + e];   // col (target)
        atomicAdd(&deg[c], ew[e]);
        atomicAdd(&cnt[c], 1);
    }
}

__global__ void dinv_kernel(float* __restrict__ deg_dinv, int N) {
    int i = blockIdx.x * blockDim.x + threadIdx.x;
    if (i < N) {
        float d = deg_dinv[i] + 1.0f;   // +1 for the self-loop weight
        deg_dinv[i] = (d > 0.0f) ? rsqrtf(d) : 0.0f;
    }
}

// --------------------------------------------- 3-phase exclusive scan ------
// Phase 1: per-block (256-wide) tree reduction of cnt -> blockSum[b]
__global__ __launch_bounds__(256) void scan_reduce(const int* __restrict__ cnt,
                                                   int* __restrict__ blockSum, int N) {
    __shared__ int s[256];
    const int t = threadIdx.x;
    const int i = blockIdx.x * 256 + t;
    s[t] = (i < N) ? cnt[i] : 0;
    __syncthreads();
#pragma unroll
    for (int off = 128; off > 0; off >>= 1) {
        if (t < off) s[t] += s[t + off];
        __syncthreads();
    }
    if (t == 0) blockSum[blockIdx.x] = s[0];
}

// Phase 2: one block scans up to 256 block sums -> exclusive blockOff, total.
__global__ __launch_bounds__(256) void scan_blocksums(int* __restrict__ blockSum,
                                                      int* __restrict__ blockOff,
                                                      int* __restrict__ row_ptr_N,
                                                      int B) {
    __shared__ int s[256];
    const int t = threadIdx.x;
    const int v = (t < B) ? blockSum[t] : 0;
    s[t] = v;
    __syncthreads();
#pragma unroll
    for (int off = 1; off < 256; off <<= 1) {
        int u = (t >= off) ? s[t - off] : 0;
        __syncthreads();
        s[t] += u;
        __syncthreads();
    }
    if (t < B) blockOff[t] = s[t] - v;          // exclusive
    if (t == 255) *row_ptr_N = s[255];           // grand total -> row_ptr[N]
}

// Phase 3: in-block exclusive scan + block offset -> row_ptr, cursor.
__global__ __launch_bounds__(256) void scan_apply(const int* __restrict__ cnt,
                                                  const int* __restrict__ blockOff,
                                                  int* __restrict__ row_ptr,
                                                  int* __restrict__ cursor, int N) {
    __shared__ int s[256];
    const int t = threadIdx.x;
    const int i = blockIdx.x * 256 + t;
    const int v = (i < N) ? cnt[i] : 0;
    s[t] = v;
    __syncthreads();
#pragma unroll
    for (int off = 1; off < 256; off <<= 1) {
        int u = (t >= off) ? s[t - off] : 0;
        __syncthreads();
        s[t] += u;
        __syncthreads();
    }
    if (i < N) {
        int ex = s[t] - v + blockOff[blockIdx.x];
        row_ptr[i] = ex;
        cursor[i] = ex;
    }
}

// ------------------------------------------------- bucket fill (CSR) -------
__global__ void fill_kernel(const int* __restrict__ ei, const float* __restrict__ ew,
                            const float* __restrict__ dinv, int* __restrict__ cursor,
                            int* __restrict__ src_s, float* __restrict__ nrm_s, int E) {
    int e = blockIdx.x * blockDim.x + threadIdx.x;
    if (e < E) {
        int r = ei[e];
        int c = ei[E + e];
        float w = dinv[r] * ew[e] * dinv[c];
        int pos = atomicAdd(&cursor[c], 1);
        src_s[pos] = r;
        nrm_s[pos] = w;
    }
}

// ------------------------------------------------------------------ GEMM ----
template <int K, int DOUT, int BN, int TN>
__global__ __launch_bounds__(256) void gemm_kernel(const float* __restrict__ X,
                                                   const float* __restrict__ W,
                                                   float* __restrict__ H, int N) {
    constexpr int BM = 64, BK = 16;
    __shared__ float As[BK][BM];
    __shared__ float Bs[BK][BN];

    const int tid = threadIdx.x;
    const int tx = tid & 15;
    const int ty = tid >> 4;
    const int row0 = blockIdx.x * BM;
    const int n0 = blockIdx.y * BN;

    float acc[4][TN];
#pragma unroll
    for (int i = 0; i < 4; ++i)
#pragma unroll
        for (int j = 0; j < TN; ++j) acc[i][j] = 0.0f;

    for (int k0 = 0; k0 < K; k0 += BK) {
        {
            int m = tid >> 2;
            int kq = (tid & 3) << 2;
            int r = row0 + m;
            float4 v = make_float4(0.f, 0.f, 0.f, 0.f);
            if (r < N) v = *(const float4*)&X[(size_t)r * K + k0 + kq];
            As[kq + 0][m] = v.x;
            As[kq + 1][m] = v.y;
            As[kq + 2][m] = v.z;
            As[kq + 3][m] = v.w;
        }
        if constexpr (BN == 64) {
            int k = tid >> 4;
            int nq = (tid & 15) << 2;
            float4 v = *(const float4*)&W[(size_t)(k0 + k) * DOUT + n0 + nq];
            *(float4*)&Bs[k][nq] = v;
        } else {  // BN == 32
            int idx = tid * 2;
            int k = idx >> 5;
            int nq = idx & 31;
            float2 v = *(const float2*)&W[(size_t)(k0 + k) * DOUT + n0 + nq];
            Bs[k][nq] = v.x;
            Bs[k][nq + 1] = v.y;
        }
        __syncthreads();

#pragma unroll
        for (int k = 0; k < BK; ++k) {
            float a[4];
            *(float4*)a = *(const float4*)&As[k][ty * 4];
            float b[TN];
            if constexpr (TN == 4) {
                *(float4*)b = *(const float4*)&Bs[k][tx * 4];
            } else {
                float2 t2 = *(const float2*)&Bs[k][tx * 2];
                b[0] = t2.x; b[1] = t2.y;
            }
#pragma unroll
            for (int i = 0; i < 4; ++i)
#pragma unroll
                for (int j = 0; j < TN; ++j) acc[i][j] = fmaf(a[i], b[j], acc[i][j]);
        }
        __syncthreads();
    }

#pragma unroll
    for (int i = 0; i < 4; ++i) {
        int r = row0 + ty * 4 + i;
        if (r < N) {
            float* dst = &H[(size_t)r * DOUT + n0 + tx * TN];
            if constexpr (TN == 4) {
                *(float4*)dst = make_float4(acc[i][0], acc[i][1], acc[i][2], acc[i][3]);
            } else {
                *(float2*)dst = make_float2(acc[i][0], acc[i][1]);
            }
        }
    }
}

// -------------------------------------------- fused aggregate + epilogue ----
template <int D>
__global__ __launch_bounds__(256) void agg_kernel(const float* __restrict__ H,
                                                  const int* __restrict__ row_ptr,
                                                  const int* __restrict__ src_s,
                                                  const float* __restrict__ nrm_s,
                                                  const float* __restrict__ dinv,
                                                  const float* __restrict__ bias,
                                                  float* __restrict__ out, int N) {
    constexpr int TPN = D / 4;        // threads per node
    constexpr int NPB = 256 / TPN;    // nodes per block
    const int tid = threadIdx.x;
    const int g = tid / TPN;
    const int lane = tid % TPN;
    const int node = blockIdx.x * NPB + g;
    if (node >= N) return;

    const int beg = row_ptr[node];
    const int end = row_ptr[node + 1];
    float4 acc = make_float4(0.f, 0.f, 0.f, 0.f);
    for (int k = beg; k < end; ++k) {
        int s = src_s[k];
        float w = nrm_s[k];
        float4 h = *(const float4*)&H[(size_t)s * D + lane * 4];
        acc.x = fmaf(w, h.x, acc.x);
        acc.y = fmaf(w, h.y, acc.y);
        acc.z = fmaf(w, h.z, acc.z);
        acc.w = fmaf(w, h.w, acc.w);
    }
    float di = dinv[node];
    float d2 = di * di;
    float4 hd = *(const float4*)&H[(size_t)node * D + lane * 4];
    acc.x = fmaf(d2, hd.x, acc.x);
    acc.y = fmaf(d2, hd.y, acc.y);
    acc.z = fmaf(d2, hd.z, acc.z);
    acc.w = fmaf(d2, hd.w, acc.w);
    float4 b = *(const float4*)&bias[lane * 4];
    acc.x = fmaxf(acc.x + b.x, 0.f);
    acc.y = fmaxf(acc.y + b.y, 0.f);
    acc.z = fmaxf(acc.z + b.z, 0.f);
    acc.w = fmaxf(acc.w + b.w, 0.f);
    *(float4*)&out[(size_t)node * D + lane * 4] = acc;
}

// ---------------------------------------------------------------- launch ----
extern "C" void kernel_launch(void* const* d_in, const int* in_sizes, int n_in,
                              void* d_out, int out_size, void* d_ws, size_t ws_size,
                              hipStream_t stream) {
    const float* x   = (const float*)d_in[0];
    const int* ei    = (const int*)d_in[1];
    const float* ew  = (const float*)d_in[2];
    const float* W1  = (const float*)d_in[3];
    const float* b1  = (const float*)d_in[4];
    const float* W2  = (const float*)d_in[5];
    const float* b2  = (const float*)d_in[6];
    const float* W3  = (const float*)d_in[7];
    const float* b3  = (const float*)d_in[8];
    float* out = (float*)d_out;

    const int N = in_sizes[0] / D0;   // 50000
    const int E = in_sizes[2];        // 800000
    (void)n_in; (void)out_size; (void)ws_size;

    // ---- workspace carving ----
    char* ws = (char*)d_ws;
    size_t off = 0;
    auto carve = [&](size_t bytes) -> void* {
        void* p = (void*)(ws + off);
        off += (bytes + 255) & ~(size_t)255;
        return p;
    };
    float* dinv    = (float*)carve((size_t)N * 4);
    int*   cnt     = (int*)carve((size_t)N * 4);
    int*   row_ptr = (int*)carve((size_t)(N + 1) * 4);
    int*   cursor  = (int*)carve((size_t)N * 4);
    int*   bsum    = (int*)carve(256 * 4);
    int*   boff    = (int*)carve(256 * 4);
    int*   src_s   = (int*)carve((size_t)E * 4);
    float* nrm_s   = (float*)carve((size_t)E * 4);
    float* bufA    = (float*)carve((size_t)N * D1 * 4);   // 25.6 MB
    float* bufB    = (float*)carve((size_t)N * D1 * 4);   // 25.6 MB

    float* h1   = bufA;                  // N x 128
    float* out1 = bufB;                  // N x 128 ; x for layer 2
    float* h2   = bufA;                  // N x 64
    float* out2 = bufA + (size_t)N * D2; // N x 64 ; x for layer 3
    float* h3   = bufB;                  // N x 32

    const int eb = (E + 255) / 256;
    const int nb = (N + 255) / 256;
    const int rowBlocks = (N + 63) / 64;
    const int scanB = (N + 255) / 256;   // 196 blocks (must be <= 256)

    // ---- CSR build + normalization ----
    hipMemsetAsync(dinv, 0, (size_t)N * 4, stream);
    hipMemsetAsync(cnt, 0, (size_t)N * 4, stream);
    deg_hist_kernel<<<eb, 256, 0, stream>>>(ei, ew, dinv, cnt, E);
    dinv_kernel<<<nb, 256, 0, stream>>>(dinv, N);
    scan_reduce<<<scanB, 256, 0, stream>>>(cnt, bsum, N);
    scan_blocksums<<<1, 256, 0, stream>>>(bsum, boff, &row_ptr[N], scanB);
    scan_apply<<<scanB, 256, 0, stream>>>(cnt, boff, row_ptr, cursor, N);
    fill_kernel<<<eb, 256, 0, stream>>>(ei, ew, dinv, cursor, src_s, nrm_s, E);

    // ---- layer 1: 256 -> 128 ----
    gemm_kernel<D0, D1, 64, 4><<<dim3(rowBlocks, 2), 256, 0, stream>>>(x, W1, h1, N);
    agg_kernel<D1><<<(N + 7) / 8, 256, 0, stream>>>(h1, row_ptr, src_s, nrm_s, dinv, b1, out1, N);

    // ---- layer 2: 128 -> 64 ----
    gemm_kernel<D1, D2, 64, 4><<<dim3(rowBlocks, 1), 256, 0, stream>>>(out1, W2, h2, N);
    agg_kernel<D2><<<(N + 15) / 16, 256, 0, stream>>>(h2, row_ptr, src_s, nrm_s, dinv, b2, out2, N);

    // ---- layer 3: 64 -> 32 ----
    gemm_kernel<D2, D3, 32, 2><<<dim3(rowBlocks, 1), 256, 0, stream>>>(out2, W3, h3, N);
    agg_kernel<D3><<<(N + 31) / 32, 256, 0, stream>>>(h3, row_ptr, src_s, nrm_s, dinv, b3, out, N);
}

// Round 5
// 404.288 us; speedup vs baseline: 2.1611x; 1.0805x over previous
//
#include <hip/hip_runtime.h>

// GCN encoder: 3x (GCNConv + ReLU), dims 256->128->64->32
// N=50000 nodes, E=800000 edges, fp32. edge_index delivered as int32 (harness).
// R2: CSR gather instead of atomic scatter.
// R3: multi-block 3-phase scan.
// R4: packed 64-bit deg+cnt atomic (halves atomic traffic), int2 CSR payload,
//     8x4 GEMM microtile (BM=128).

#define D0 256
#define D1 128
#define D2 64
#define D3 32

#define FIX_SCALE 16777216.0f           // 2^24 fixed-point for degree
#define FIX_INV   (1.0f / 16777216.0f)

// ------------------------------------------------- degree + histogram ------
// One packed atomic per edge: high 32 bits = count, low 32 bits = fixed-point
// weighted degree. Max degree ~45 => low sum < 2^30, no carry into count.
__global__ void deg_hist_kernel(const int* __restrict__ ei, const float* __restrict__ ew,
                                unsigned long long* __restrict__ pk, int E) {
    int e = blockIdx.x * blockDim.x + threadIdx.x;
    if (e < E) {
        int c = ei[E + e];   // col (target)
        unsigned int wfix = (unsigned int)(ew[e] * FIX_SCALE + 0.5f);
        atomicAdd(&pk[c], (1ULL << 32) | (unsigned long long)wfix);
    }
}

// unpack: dinv = rsqrt(deg+1), cnt for the scan
__global__ void dinv_cnt_kernel(const unsigned long long* __restrict__ pk,
                                float* __restrict__ dinv, int* __restrict__ cnt, int N) {
    int i = blockIdx.x * blockDim.x + threadIdx.x;
    if (i < N) {
        unsigned long long p = pk[i];
        float d = (float)(unsigned int)(p & 0xffffffffULL) * FIX_INV + 1.0f;  // +1 self-loop
        dinv[i] = rsqrtf(d);            // d >= 1 always
        cnt[i] = (int)(p >> 32);
    }
}

// --------------------------------------------- 3-phase exclusive scan ------
__global__ __launch_bounds__(256) void scan_reduce(const int* __restrict__ cnt,
                                                   int* __restrict__ blockSum, int N) {
    __shared__ int s[256];
    const int t = threadIdx.x;
    const int i = blockIdx.x * 256 + t;
    s[t] = (i < N) ? cnt[i] : 0;
    __syncthreads();
#pragma unroll
    for (int off = 128; off > 0; off >>= 1) {
        if (t < off) s[t] += s[t + off];
        __syncthreads();
    }
    if (t == 0) blockSum[blockIdx.x] = s[0];
}

__global__ __launch_bounds__(256) void scan_blocksums(int* __restrict__ blockSum,
                                                      int* __restrict__ blockOff,
                                                      int* __restrict__ row_ptr_N,
                                                      int B) {
    __shared__ int s[256];
    const int t = threadIdx.x;
    const int v = (t < B) ? blockSum[t] : 0;
    s[t] = v;
    __syncthreads();
#pragma unroll
    for (int off = 1; off < 256; off <<= 1) {
        int u = (t >= off) ? s[t - off] : 0;
        __syncthreads();
        s[t] += u;
        __syncthreads();
    }
    if (t < B) blockOff[t] = s[t] - v;
    if (t == 255) *row_ptr_N = s[255];
}

__global__ __launch_bounds__(256) void scan_apply(const int* __restrict__ cnt,
                                                  const int* __restrict__ blockOff,
                                                  int* __restrict__ row_ptr,
                                                  int* __restrict__ cursor, int N) {
    __shared__ int s[256];
    const int t = threadIdx.x;
    const int i = blockIdx.x * 256 + t;
    const int v = (i < N) ? cnt[i] : 0;
    s[t] = v;
    __syncthreads();
#pragma unroll
    for (int off = 1; off < 256; off <<= 1) {
        int u = (t >= off) ? s[t - off] : 0;
        __syncthreads();
        s[t] += u;
        __syncthreads();
    }
    if (i < N) {
        int ex = s[t] - v + blockOff[blockIdx.x];
        row_ptr[i] = ex;
        cursor[i] = ex;
    }
}

// ------------------------------------------------- bucket fill (CSR) -------
// One 8B interleaved (src, norm) store per edge instead of two 4B stores.
__global__ void fill_kernel(const int* __restrict__ ei, const float* __restrict__ ew,
                            const float* __restrict__ dinv, int* __restrict__ cursor,
                            int2* __restrict__ pairs, int E) {
    int e = blockIdx.x * blockDim.x + threadIdx.x;
    if (e < E) {
        int r = ei[e];
        int c = ei[E + e];
        float w = dinv[r] * ew[e] * dinv[c];
        int pos = atomicAdd(&cursor[c], 1);
        pairs[pos] = make_int2(r, __float_as_int(w));
    }
}

// ---------------------------------------------------------- GEMM (BM=128) --
// H[N,DOUT] = X[N,K] @ W[K,DOUT]. 128x64 tile, 256 threads, 8x4 microtile.
template <int K, int DOUT>
__global__ __launch_bounds__(256) void gemm128_kernel(const float* __restrict__ X,
                                                      const float* __restrict__ W,
                                                      float* __restrict__ H, int N) {
    constexpr int BM = 128, BN = 64, BK = 16;
    __shared__ float As[BK][BM];
    __shared__ float Bs[BK][BN];

    const int tid = threadIdx.x;
    const int tx = tid & 15;    // col group: 4 cols
    const int ty = tid >> 4;    // row group: 8 rows
    const int row0 = blockIdx.x * BM;
    const int n0 = blockIdx.y * BN;

    float acc[8][4];
#pragma unroll
    for (int i = 0; i < 8; ++i)
#pragma unroll
        for (int j = 0; j < 4; ++j) acc[i][j] = 0.0f;

    for (int k0 = 0; k0 < K; k0 += BK) {
        {
            int m = tid >> 2;             // 0..63
            int kq = (tid & 3) << 2;      // 0,4,8,12
#pragma unroll
            for (int h = 0; h < 2; ++h) {
                int mm = m + h * 64;
                int r = row0 + mm;
                float4 v = make_float4(0.f, 0.f, 0.f, 0.f);
                if (r < N) v = *(const float4*)&X[(size_t)r * K + k0 + kq];
                As[kq + 0][mm] = v.x;
                As[kq + 1][mm] = v.y;
                As[kq + 2][mm] = v.z;
                As[kq + 3][mm] = v.w;
            }
        }
        {
            int k = tid >> 4;
            int nq = (tid & 15) << 2;
            *(float4*)&Bs[k][nq] = *(const float4*)&W[(size_t)(k0 + k) * DOUT + n0 + nq];
        }
        __syncthreads();

#pragma unroll
        for (int k = 0; k < BK; ++k) {
            float a[8], b[4];
            *(float4*)&a[0] = *(const float4*)&As[k][ty * 8];
            *(float4*)&a[4] = *(const float4*)&As[k][ty * 8 + 4];
            *(float4*)&b[0] = *(const float4*)&Bs[k][tx * 4];
#pragma unroll
            for (int i = 0; i < 8; ++i)
#pragma unroll
                for (int j = 0; j < 4; ++j) acc[i][j] = fmaf(a[i], b[j], acc[i][j]);
        }
        __syncthreads();
    }

#pragma unroll
    for (int i = 0; i < 8; ++i) {
        int r = row0 + ty * 8 + i;
        if (r < N)
            *(float4*)&H[(size_t)r * DOUT + n0 + tx * 4] =
                make_float4(acc[i][0], acc[i][1], acc[i][2], acc[i][3]);
    }
}

// ------------------------------------------------------- GEMM (small, L3) --
template <int K, int DOUT, int BN, int TN>
__global__ __launch_bounds__(256) void gemm_kernel(const float* __restrict__ X,
                                                   const float* __restrict__ W,
                                                   float* __restrict__ H, int N) {
    constexpr int BM = 64, BK = 16;
    __shared__ float As[BK][BM];
    __shared__ float Bs[BK][BN];

    const int tid = threadIdx.x;
    const int tx = tid & 15;
    const int ty = tid >> 4;
    const int row0 = blockIdx.x * BM;
    const int n0 = blockIdx.y * BN;

    float acc[4][TN];
#pragma unroll
    for (int i = 0; i < 4; ++i)
#pragma unroll
        for (int j = 0; j < TN; ++j) acc[i][j] = 0.0f;

    for (int k0 = 0; k0 < K; k0 += BK) {
        {
            int m = tid >> 2;
            int kq = (tid & 3) << 2;
            int r = row0 + m;
            float4 v = make_float4(0.f, 0.f, 0.f, 0.f);
            if (r < N) v = *(const float4*)&X[(size_t)r * K + k0 + kq];
            As[kq + 0][m] = v.x;
            As[kq + 1][m] = v.y;
            As[kq + 2][m] = v.z;
            As[kq + 3][m] = v.w;
        }
        {
            int idx = tid * 2;
            int k = idx >> 5;
            int nq = idx & 31;
            float2 v = *(const float2*)&W[(size_t)(k0 + k) * DOUT + n0 + nq];
            Bs[k][nq] = v.x;
            Bs[k][nq + 1] = v.y;
        }
        __syncthreads();

#pragma unroll
        for (int k = 0; k < BK; ++k) {
            float a[4];
            *(float4*)a = *(const float4*)&As[k][ty * 4];
            float b[TN];
            float2 t2 = *(const float2*)&Bs[k][tx * 2];
            b[0] = t2.x; b[1] = t2.y;
#pragma unroll
            for (int i = 0; i < 4; ++i)
#pragma unroll
                for (int j = 0; j < TN; ++j) acc[i][j] = fmaf(a[i], b[j], acc[i][j]);
        }
        __syncthreads();
    }

#pragma unroll
    for (int i = 0; i < 4; ++i) {
        int r = row0 + ty * 4 + i;
        if (r < N) {
            float* dst = &H[(size_t)r * DOUT + n0 + tx * TN];
            *(float2*)dst = make_float2(acc[i][0], acc[i][1]);
        }
    }
}

// -------------------------------------------- fused aggregate + epilogue ----
template <int D>
__global__ __launch_bounds__(256) void agg_kernel(const float* __restrict__ H,
                                                  const int* __restrict__ row_ptr,
                                                  const int2* __restrict__ pairs,
                                                  const float* __restrict__ dinv,
                                                  const float* __restrict__ bias,
                                                  float* __restrict__ out, int N) {
    constexpr int TPN = D / 4;        // threads per node
    constexpr int NPB = 256 / TPN;    // nodes per block
    const int tid = threadIdx.x;
    const int g = tid / TPN;
    const int lane = tid % TPN;
    const int node = blockIdx.x * NPB + g;
    if (node >= N) return;

    const int beg = row_ptr[node];
    const int end = row_ptr[node + 1];
    float4 acc = make_float4(0.f, 0.f, 0.f, 0.f);
    for (int k = beg; k < end; ++k) {
        int2 p = pairs[k];
        int s = p.x;
        float w = __int_as_float(p.y);
        float4 h = *(const float4*)&H[(size_t)s * D + lane * 4];
        acc.x = fmaf(w, h.x, acc.x);
        acc.y = fmaf(w, h.y, acc.y);
        acc.z = fmaf(w, h.z, acc.z);
        acc.w = fmaf(w, h.w, acc.w);
    }
    float di = dinv[node];
    float d2 = di * di;
    float4 hd = *(const float4*)&H[(size_t)node * D + lane * 4];
    acc.x = fmaf(d2, hd.x, acc.x);
    acc.y = fmaf(d2, hd.y, acc.y);
    acc.z = fmaf(d2, hd.z, acc.z);
    acc.w = fmaf(d2, hd.w, acc.w);
    float4 b = *(const float4*)&bias[lane * 4];
    acc.x = fmaxf(acc.x + b.x, 0.f);
    acc.y = fmaxf(acc.y + b.y, 0.f);
    acc.z = fmaxf(acc.z + b.z, 0.f);
    acc.w = fmaxf(acc.w + b.w, 0.f);
    *(float4*)&out[(size_t)node * D + lane * 4] = acc;
}

// ---------------------------------------------------------------- launch ----
extern "C" void kernel_launch(void* const* d_in, const int* in_sizes, int n_in,
                              void* d_out, int out_size, void* d_ws, size_t ws_size,
                              hipStream_t stream) {
    const float* x   = (const float*)d_in[0];
    const int* ei    = (const int*)d_in[1];
    const float* ew  = (const float*)d_in[2];
    const float* W1  = (const float*)d_in[3];
    const float* b1  = (const float*)d_in[4];
    const float* W2  = (const float*)d_in[5];
    const float* b2  = (const float*)d_in[6];
    const float* W3  = (const float*)d_in[7];
    const float* b3  = (const float*)d_in[8];
    float* out = (float*)d_out;

    const int N = in_sizes[0] / D0;   // 50000
    const int E = in_sizes[2];        // 800000
    (void)n_in; (void)out_size; (void)ws_size;

    // ---- workspace carving ----
    char* ws = (char*)d_ws;
    size_t off = 0;
    auto carve = [&](size_t bytes) -> void* {
        void* p = (void*)(ws + off);
        off += (bytes + 255) & ~(size_t)255;
        return p;
    };
    unsigned long long* pk = (unsigned long long*)carve((size_t)N * 8);
    float* dinv    = (float*)carve((size_t)N * 4);
    int*   cnt     = (int*)carve((size_t)N * 4);
    int*   row_ptr = (int*)carve((size_t)(N + 1) * 4);
    int*   cursor  = (int*)carve((size_t)N * 4);
    int*   bsum    = (int*)carve(256 * 4);
    int*   boff    = (int*)carve(256 * 4);
    int2*  pairs   = (int2*)carve((size_t)E * 8);
    float* bufA    = (float*)carve((size_t)N * D1 * 4);   // 25.6 MB
    float* bufB    = (float*)carve((size_t)N * D1 * 4);   // 25.6 MB

    float* h1   = bufA;                  // N x 128
    float* out1 = bufB;                  // N x 128 ; x for layer 2
    float* h2   = bufA;                  // N x 64
    float* out2 = bufA + (size_t)N * D2; // N x 64 ; x for layer 3
    float* h3   = bufB;                  // N x 32

    const int eb = (E + 255) / 256;
    const int nb = (N + 255) / 256;
    const int rb128 = (N + 127) / 128;
    const int rb64 = (N + 63) / 64;
    const int scanB = (N + 255) / 256;   // must be <= 256

    // ---- CSR build + normalization ----
    hipMemsetAsync(pk, 0, (size_t)N * 8, stream);
    deg_hist_kernel<<<eb, 256, 0, stream>>>(ei, ew, pk, E);
    dinv_cnt_kernel<<<nb, 256, 0, stream>>>(pk, dinv, cnt, N);
    scan_reduce<<<scanB, 256, 0, stream>>>(cnt, bsum, N);
    scan_blocksums<<<1, 256, 0, stream>>>(bsum, boff, &row_ptr[N], scanB);
    scan_apply<<<scanB, 256, 0, stream>>>(cnt, boff, row_ptr, cursor, N);
    fill_kernel<<<eb, 256, 0, stream>>>(ei, ew, dinv, cursor, pairs, E);

    // ---- layer 1: 256 -> 128 ----
    gemm128_kernel<D0, D1><<<dim3(rb128, 2), 256, 0, stream>>>(x, W1, h1, N);
    agg_kernel<D1><<<(N + 7) / 8, 256, 0, stream>>>(h1, row_ptr, pairs, dinv, b1, out1, N);

    // ---- layer 2: 128 -> 64 ----
    gemm128_kernel<D1, D2><<<dim3(rb128, 1), 256, 0, stream>>>(out1, W2, h2, N);
    agg_kernel<D2><<<(N + 15) / 16, 256, 0, stream>>>(h2, row_ptr, pairs, dinv, b2, out2, N);

    // ---- layer 3: 64 -> 32 ----
    gemm_kernel<D2, D3, 32, 2><<<dim3(rb64, 1), 256, 0, stream>>>(out2, W3, h3, N);
    agg_kernel<D3><<<(N + 31) / 32, 256, 0, stream>>>(h3, row_ptr, pairs, dinv, b3, out, N);
}

// Round 6
// 362.741 us; speedup vs baseline: 2.4087x; 1.1145x over previous
//
#include <hip/hip_runtime.h>
#include <hip/hip_fp16.h>

// GCN encoder: 3x (GCNConv + ReLU), dims 256->128->64->32
// N=50000 nodes, E=800000 edges. edge_index delivered as int32 (harness).
// R2: CSR gather instead of atomic scatter.
// R3: multi-block 3-phase scan.
// R4: packed 64-bit deg+cnt atomic, int2 CSR payload, 8x4 GEMM microtile.
// R5: fp16 H gather buffer (halves agg fetch traffic), dinv fused into scan.

#define D0 256
#define D1 128
#define D2 64
#define D3 32

#define FIX_SCALE 16777216.0f           // 2^24 fixed-point for degree
#define FIX_INV   (1.0f / 16777216.0f)

// ------------------------------------------------- degree + histogram ------
__global__ void deg_hist_kernel(const int* __restrict__ ei, const float* __restrict__ ew,
                                unsigned long long* __restrict__ pk, int E) {
    int e = blockIdx.x * blockDim.x + threadIdx.x;
    if (e < E) {
        int c = ei[E + e];   // col (target)
        unsigned int wfix = (unsigned int)(ew[e] * FIX_SCALE + 0.5f);
        atomicAdd(&pk[c], (1ULL << 32) | (unsigned long long)wfix);
    }
}

// --------------------------------------------- 3-phase exclusive scan ------
// Phase 1 (fused): unpack pk -> dinv, cnt; per-block reduce cnt -> blockSum.
__global__ __launch_bounds__(256) void scan_reduce(const unsigned long long* __restrict__ pk,
                                                   float* __restrict__ dinv,
                                                   int* __restrict__ cnt,
                                                   int* __restrict__ blockSum, int N) {
    __shared__ int s[256];
    const int t = threadIdx.x;
    const int i = blockIdx.x * 256 + t;
    int v = 0;
    if (i < N) {
        unsigned long long p = pk[i];
        float d = (float)(unsigned int)(p & 0xffffffffULL) * FIX_INV + 1.0f;  // +1 self-loop
        dinv[i] = rsqrtf(d);
        v = (int)(p >> 32);
        cnt[i] = v;
    }
    s[t] = v;
    __syncthreads();
#pragma unroll
    for (int off = 128; off > 0; off >>= 1) {
        if (t < off) s[t] += s[t + off];
        __syncthreads();
    }
    if (t == 0) blockSum[blockIdx.x] = s[0];
}

__global__ __launch_bounds__(256) void scan_blocksums(int* __restrict__ blockSum,
                                                      int* __restrict__ blockOff,
                                                      int* __restrict__ row_ptr_N,
                                                      int B) {
    __shared__ int s[256];
    const int t = threadIdx.x;
    const int v = (t < B) ? blockSum[t] : 0;
    s[t] = v;
    __syncthreads();
#pragma unroll
    for (int off = 1; off < 256; off <<= 1) {
        int u = (t >= off) ? s[t - off] : 0;
        __syncthreads();
        s[t] += u;
        __syncthreads();
    }
    if (t < B) blockOff[t] = s[t] - v;
    if (t == 255) *row_ptr_N = s[255];
}

__global__ __launch_bounds__(256) void scan_apply(const int* __restrict__ cnt,
                                                  const int* __restrict__ blockOff,
                                                  int* __restrict__ row_ptr,
                                                  int* __restrict__ cursor, int N) {
    __shared__ int s[256];
    const int t = threadIdx.x;
    const int i = blockIdx.x * 256 + t;
    const int v = (i < N) ? cnt[i] : 0;
    s[t] = v;
    __syncthreads();
#pragma unroll
    for (int off = 1; off < 256; off <<= 1) {
        int u = (t >= off) ? s[t - off] : 0;
        __syncthreads();
        s[t] += u;
        __syncthreads();
    }
    if (i < N) {
        int ex = s[t] - v + blockOff[blockIdx.x];
        row_ptr[i] = ex;
        cursor[i] = ex;
    }
}

// ------------------------------------------------- bucket fill (CSR) -------
__global__ void fill_kernel(const int* __restrict__ ei, const float* __restrict__ ew,
                            const float* __restrict__ dinv, int* __restrict__ cursor,
                            int2* __restrict__ pairs, int E) {
    int e = blockIdx.x * blockDim.x + threadIdx.x;
    if (e < E) {
        int r = ei[e];
        int c = ei[E + e];
        float w = dinv[r] * ew[e] * dinv[c];
        int pos = atomicAdd(&cursor[c], 1);
        pairs[pos] = make_int2(r, __float_as_int(w));
    }
}

// ---------------------------------------------------------- GEMM (BM=128) --
// H[N,DOUT] (fp16) = X[N,K] (fp32) @ W[K,DOUT]. 128x64 tile, 8x4 microtile.
template <int K, int DOUT>
__global__ __launch_bounds__(256) void gemm128_kernel(const float* __restrict__ X,
                                                      const float* __restrict__ W,
                                                      __half* __restrict__ H, int N) {
    constexpr int BM = 128, BN = 64, BK = 16;
    __shared__ float As[BK][BM];
    __shared__ float Bs[BK][BN];

    const int tid = threadIdx.x;
    const int tx = tid & 15;    // col group: 4 cols
    const int ty = tid >> 4;    // row group: 8 rows
    const int row0 = blockIdx.x * BM;
    const int n0 = blockIdx.y * BN;

    float acc[8][4];
#pragma unroll
    for (int i = 0; i < 8; ++i)
#pragma unroll
        for (int j = 0; j < 4; ++j) acc[i][j] = 0.0f;

    for (int k0 = 0; k0 < K; k0 += BK) {
        {
            int m = tid >> 2;             // 0..63
            int kq = (tid & 3) << 2;      // 0,4,8,12
#pragma unroll
            for (int h = 0; h < 2; ++h) {
                int mm = m + h * 64;
                int r = row0 + mm;
                float4 v = make_float4(0.f, 0.f, 0.f, 0.f);
                if (r < N) v = *(const float4*)&X[(size_t)r * K + k0 + kq];
                As[kq + 0][mm] = v.x;
                As[kq + 1][mm] = v.y;
                As[kq + 2][mm] = v.z;
                As[kq + 3][mm] = v.w;
            }
        }
        {
            int k = tid >> 4;
            int nq = (tid & 15) << 2;
            *(float4*)&Bs[k][nq] = *(const float4*)&W[(size_t)(k0 + k) * DOUT + n0 + nq];
        }
        __syncthreads();

#pragma unroll
        for (int k = 0; k < BK; ++k) {
            float a[8], b[4];
            *(float4*)&a[0] = *(const float4*)&As[k][ty * 8];
            *(float4*)&a[4] = *(const float4*)&As[k][ty * 8 + 4];
            *(float4*)&b[0] = *(const float4*)&Bs[k][tx * 4];
#pragma unroll
            for (int i = 0; i < 8; ++i)
#pragma unroll
                for (int j = 0; j < 4; ++j) acc[i][j] = fmaf(a[i], b[j], acc[i][j]);
        }
        __syncthreads();
    }

#pragma unroll
    for (int i = 0; i < 8; ++i) {
        int r = row0 + ty * 8 + i;
        if (r < N) {
            union { __half2 h[2]; int2 v; } u;
            u.h[0] = __halves2half2(__float2half(acc[i][0]), __float2half(acc[i][1]));
            u.h[1] = __halves2half2(__float2half(acc[i][2]), __float2half(acc[i][3]));
            *(int2*)&H[(size_t)r * DOUT + n0 + tx * 4] = u.v;
        }
    }
}

// ------------------------------------------------------- GEMM (64->32) -----
template <int K, int DOUT>
__global__ __launch_bounds__(256) void gemm_small_kernel(const float* __restrict__ X,
                                                         const float* __restrict__ W,
                                                         __half* __restrict__ H, int N) {
    constexpr int BM = 64, BN = 32, BK = 16;
    __shared__ float As[BK][BM];
    __shared__ float Bs[BK][BN];

    const int tid = threadIdx.x;
    const int tx = tid & 15;
    const int ty = tid >> 4;
    const int row0 = blockIdx.x * BM;

    float acc[4][2];
#pragma unroll
    for (int i = 0; i < 4; ++i) { acc[i][0] = 0.f; acc[i][1] = 0.f; }

    for (int k0 = 0; k0 < K; k0 += BK) {
        {
            int m = tid >> 2;
            int kq = (tid & 3) << 2;
            int r = row0 + m;
            float4 v = make_float4(0.f, 0.f, 0.f, 0.f);
            if (r < N) v = *(const float4*)&X[(size_t)r * K + k0 + kq];
            As[kq + 0][m] = v.x;
            As[kq + 1][m] = v.y;
            As[kq + 2][m] = v.z;
            As[kq + 3][m] = v.w;
        }
        {
            int idx = tid * 2;
            int k = idx >> 5;
            int nq = idx & 31;
            float2 v = *(const float2*)&W[(size_t)(k0 + k) * DOUT + nq];
            Bs[k][nq] = v.x;
            Bs[k][nq + 1] = v.y;
        }
        __syncthreads();

#pragma unroll
        for (int k = 0; k < BK; ++k) {
            float a[4];
            *(float4*)a = *(const float4*)&As[k][ty * 4];
            float2 b = *(const float2*)&Bs[k][tx * 2];
#pragma unroll
            for (int i = 0; i < 4; ++i) {
                acc[i][0] = fmaf(a[i], b.x, acc[i][0]);
                acc[i][1] = fmaf(a[i], b.y, acc[i][1]);
            }
        }
        __syncthreads();
    }

#pragma unroll
    for (int i = 0; i < 4; ++i) {
        int r = row0 + ty * 4 + i;
        if (r < N)
            *(__half2*)&H[(size_t)r * DOUT + tx * 2] =
                __halves2half2(__float2half(acc[i][0]), __float2half(acc[i][1]));
    }
}

// -------------------------------------------- fused aggregate + epilogue ----
// out[c][:] = relu( sum nrm*H[src] + dinv[c]^2*H[c] + b ).  H is fp16,
// D/8 lanes per node (16B loads), fp32 accumulation, fp32 out.
template <int D>
__global__ __launch_bounds__(256) void agg_kernel(const __half* __restrict__ H,
                                                  const int* __restrict__ row_ptr,
                                                  const int2* __restrict__ pairs,
                                                  const float* __restrict__ dinv,
                                                  const float* __restrict__ bias,
                                                  float* __restrict__ out, int N) {
    constexpr int TPN = D / 8;        // threads per node (8 halves = 16B each)
    constexpr int NPB = 256 / TPN;    // nodes per block
    const int tid = threadIdx.x;
    const int g = tid / TPN;
    const int lane = tid % TPN;
    const int node = blockIdx.x * NPB + g;
    if (node >= N) return;

    const int beg = row_ptr[node];
    const int end = row_ptr[node + 1];
    float acc[8];
#pragma unroll
    for (int j = 0; j < 8; ++j) acc[j] = 0.0f;

    union H8 { int4 v; __half2 h[4]; };
    for (int k = beg; k < end; ++k) {
        int2 p = pairs[k];
        float w = __int_as_float(p.y);
        H8 u; u.v = *(const int4*)&H[(size_t)p.x * D + lane * 8];
#pragma unroll
        for (int q = 0; q < 4; ++q) {
            float2 f = __half22float2(u.h[q]);
            acc[2 * q]     = fmaf(w, f.x, acc[2 * q]);
            acc[2 * q + 1] = fmaf(w, f.y, acc[2 * q + 1]);
        }
    }
    // self-loop + bias + relu
    float di = dinv[node];
    float d2 = di * di;
    {
        H8 u; u.v = *(const int4*)&H[(size_t)node * D + lane * 8];
#pragma unroll
        for (int q = 0; q < 4; ++q) {
            float2 f = __half22float2(u.h[q]);
            acc[2 * q]     = fmaf(d2, f.x, acc[2 * q]);
            acc[2 * q + 1] = fmaf(d2, f.y, acc[2 * q + 1]);
        }
    }
    float b[8];
    *(float4*)&b[0] = *(const float4*)&bias[lane * 8];
    *(float4*)&b[4] = *(const float4*)&bias[lane * 8 + 4];
    float4 o0, o1;
    o0.x = fmaxf(acc[0] + b[0], 0.f);
    o0.y = fmaxf(acc[1] + b[1], 0.f);
    o0.z = fmaxf(acc[2] + b[2], 0.f);
    o0.w = fmaxf(acc[3] + b[3], 0.f);
    o1.x = fmaxf(acc[4] + b[4], 0.f);
    o1.y = fmaxf(acc[5] + b[5], 0.f);
    o1.z = fmaxf(acc[6] + b[6], 0.f);
    o1.w = fmaxf(acc[7] + b[7], 0.f);
    float* dst = &out[(size_t)node * D + lane * 8];
    *(float4*)&dst[0] = o0;
    *(float4*)&dst[4] = o1;
}

// ---------------------------------------------------------------- launch ----
extern "C" void kernel_launch(void* const* d_in, const int* in_sizes, int n_in,
                              void* d_out, int out_size, void* d_ws, size_t ws_size,
                              hipStream_t stream) {
    const float* x   = (const float*)d_in[0];
    const int* ei    = (const int*)d_in[1];
    const float* ew  = (const float*)d_in[2];
    const float* W1  = (const float*)d_in[3];
    const float* b1  = (const float*)d_in[4];
    const float* W2  = (const float*)d_in[5];
    const float* b2  = (const float*)d_in[6];
    const float* W3  = (const float*)d_in[7];
    const float* b3  = (const float*)d_in[8];
    float* out = (float*)d_out;

    const int N = in_sizes[0] / D0;   // 50000
    const int E = in_sizes[2];        // 800000
    (void)n_in; (void)out_size; (void)ws_size;

    // ---- workspace carving ----
    char* ws = (char*)d_ws;
    size_t off = 0;
    auto carve = [&](size_t bytes) -> void* {
        void* p = (void*)(ws + off);
        off += (bytes + 255) & ~(size_t)255;
        return p;
    };
    unsigned long long* pk = (unsigned long long*)carve((size_t)N * 8);
    float* dinv    = (float*)carve((size_t)N * 4);
    int*   cnt     = (int*)carve((size_t)N * 4);
    int*   row_ptr = (int*)carve((size_t)(N + 1) * 4);
    int*   cursor  = (int*)carve((size_t)N * 4);
    int*   bsum    = (int*)carve(256 * 4);
    int*   boff    = (int*)carve(256 * 4);
    int2*  pairs   = (int2*)carve((size_t)E * 8);
    __half* bufH   = (__half*)carve((size_t)N * D1 * 2);  // 12.8 MB (h1/h2/h3)
    float*  bufO   = (float*)carve((size_t)N * D1 * 4);   // 25.6 MB (out1/out2)

    __half* h1   = bufH;                 // N x 128 fp16
    float*  out1 = bufO;                 // N x 128 fp32 ; x for layer 2
    __half* h2   = bufH;                 // N x 64 fp16 (h1 dead)
    float*  out2 = bufO;                 // N x 64 fp32 (out1 dead after gemm2)
    __half* h3   = bufH;                 // N x 32 fp16 (h2 dead)

    const int eb = (E + 255) / 256;
    const int rb128 = (N + 127) / 128;
    const int rb64 = (N + 63) / 64;
    const int scanB = (N + 255) / 256;   // must be <= 256

    // ---- CSR build + normalization ----
    hipMemsetAsync(pk, 0, (size_t)N * 8, stream);
    deg_hist_kernel<<<eb, 256, 0, stream>>>(ei, ew, pk, E);
    scan_reduce<<<scanB, 256, 0, stream>>>(pk, dinv, cnt, bsum, N);
    scan_blocksums<<<1, 256, 0, stream>>>(bsum, boff, &row_ptr[N], scanB);
    scan_apply<<<scanB, 256, 0, stream>>>(cnt, boff, row_ptr, cursor, N);
    fill_kernel<<<eb, 256, 0, stream>>>(ei, ew, dinv, cursor, pairs, E);

    // ---- layer 1: 256 -> 128 ----
    gemm128_kernel<D0, D1><<<dim3(rb128, 2), 256, 0, stream>>>(x, W1, h1, N);
    agg_kernel<D1><<<(N + 15) / 16, 256, 0, stream>>>(h1, row_ptr, pairs, dinv, b1, out1, N);

    // ---- layer 2: 128 -> 64 ----
    gemm128_kernel<D1, D2><<<dim3(rb128, 1), 256, 0, stream>>>(out1, W2, h2, N);
    agg_kernel<D2><<<(N + 31) / 32, 256, 0, stream>>>(h2, row_ptr, pairs, dinv, b2, out2, N);

    // ---- layer 3: 64 -> 32 ----
    gemm_small_kernel<D2, D3><<<rb64, 256, 0, stream>>>(out2, W3, h3, N);
    agg_kernel<D3><<<(N + 63) / 64, 256, 0, stream>>>(h3, row_ptr, pairs, dinv, b3, out, N);
}

// Round 7
// 329.988 us; speedup vs baseline: 2.6477x; 1.0993x over previous
//
#include <hip/hip_runtime.h>
#include <hip/hip_fp16.h>

// GCN encoder: 3x (GCNConv + ReLU), dims 256->128->64->32
// N=50000 nodes, E=800000 edges. edge_index delivered as int32 (harness).
// R2: CSR gather instead of atomic scatter.
// R3: multi-block 3-phase scan.
// R4: packed 64-bit deg+cnt atomic, int2 CSR payload.
// R5: fp16 H gather buffer, dinv fused into scan.
// R6: MFMA fp16 GEMMs (LDS-free, per-wave 16-row slabs), fp16 inter-layer
//     activations (fp32 accumulation everywhere).

#define D0 256
#define D1 128
#define D2 64
#define D3 32

#define FIX_SCALE 16777216.0f           // 2^24 fixed-point for degree
#define FIX_INV   (1.0f / 16777216.0f)

typedef _Float16 half8 __attribute__((ext_vector_type(8)));
typedef float floatx4 __attribute__((ext_vector_type(4)));

// ------------------------------------------------- degree + histogram ------
__global__ void deg_hist_kernel(const int* __restrict__ ei, const float* __restrict__ ew,
                                unsigned long long* __restrict__ pk, int E) {
    int e = blockIdx.x * blockDim.x + threadIdx.x;
    if (e < E) {
        int c = ei[E + e];   // col (target)
        unsigned int wfix = (unsigned int)(ew[e] * FIX_SCALE + 0.5f);
        atomicAdd(&pk[c], (1ULL << 32) | (unsigned long long)wfix);
    }
}

// --------------------------------------------- 3-phase exclusive scan ------
__global__ __launch_bounds__(256) void scan_reduce(const unsigned long long* __restrict__ pk,
                                                   float* __restrict__ dinv,
                                                   int* __restrict__ cnt,
                                                   int* __restrict__ blockSum, int N) {
    __shared__ int s[256];
    const int t = threadIdx.x;
    const int i = blockIdx.x * 256 + t;
    int v = 0;
    if (i < N) {
        unsigned long long p = pk[i];
        float d = (float)(unsigned int)(p & 0xffffffffULL) * FIX_INV + 1.0f;  // +1 self-loop
        dinv[i] = rsqrtf(d);
        v = (int)(p >> 32);
        cnt[i] = v;
    }
    s[t] = v;
    __syncthreads();
#pragma unroll
    for (int off = 128; off > 0; off >>= 1) {
        if (t < off) s[t] += s[t + off];
        __syncthreads();
    }
    if (t == 0) blockSum[blockIdx.x] = s[0];
}

__global__ __launch_bounds__(256) void scan_blocksums(int* __restrict__ blockSum,
                                                      int* __restrict__ blockOff,
                                                      int* __restrict__ row_ptr_N,
                                                      int B) {
    __shared__ int s[256];
    const int t = threadIdx.x;
    const int v = (t < B) ? blockSum[t] : 0;
    s[t] = v;
    __syncthreads();
#pragma unroll
    for (int off = 1; off < 256; off <<= 1) {
        int u = (t >= off) ? s[t - off] : 0;
        __syncthreads();
        s[t] += u;
        __syncthreads();
    }
    if (t < B) blockOff[t] = s[t] - v;
    if (t == 255) *row_ptr_N = s[255];
}

__global__ __launch_bounds__(256) void scan_apply(const int* __restrict__ cnt,
                                                  const int* __restrict__ blockOff,
                                                  int* __restrict__ row_ptr,
                                                  int* __restrict__ cursor, int N) {
    __shared__ int s[256];
    const int t = threadIdx.x;
    const int i = blockIdx.x * 256 + t;
    const int v = (i < N) ? cnt[i] : 0;
    s[t] = v;
    __syncthreads();
#pragma unroll
    for (int off = 1; off < 256; off <<= 1) {
        int u = (t >= off) ? s[t - off] : 0;
        __syncthreads();
        s[t] += u;
        __syncthreads();
    }
    if (i < N) {
        int ex = s[t] - v + blockOff[blockIdx.x];
        row_ptr[i] = ex;
        cursor[i] = ex;
    }
}

// ------------------------------------------------- bucket fill (CSR) -------
__global__ void fill_kernel(const int* __restrict__ ei, const float* __restrict__ ew,
                            const float* __restrict__ dinv, int* __restrict__ cursor,
                            int2* __restrict__ pairs, int E) {
    int e = blockIdx.x * blockDim.x + threadIdx.x;
    if (e < E) {
        int r = ei[e];
        int c = ei[E + e];
        float w = dinv[r] * ew[e] * dinv[c];
        int pos = atomicAdd(&cursor[c], 1);
        pairs[pos] = make_int2(r, __float_as_int(w));
    }
}

// ----------------------------------------------- W transpose+convert -------
// Wt[n][k] = (fp16) W[k][n]
template <int K, int DOUT>
__global__ void wcvt_kernel(const float* __restrict__ W, _Float16* __restrict__ Wt) {
    int idx = blockIdx.x * 256 + threadIdx.x;
    if (idx < K * DOUT) {
        int k = idx / DOUT, n = idx % DOUT;
        Wt[n * K + k] = (_Float16)W[idx];
    }
}

// ----------------------------------------------------------- MFMA GEMM -----
// H[N,BN] (fp16) = X[N,K] @ Wt^T, Wt is [BN][K] fp16. One wave per 16-row
// slab; per K-chunk of 32: A-frag direct from global (fp32 src converted
// in-register), B-frags from Wt (L2-resident), BN/16 mfma_f32_16x16x32_f16.
// A[m=lane&15][k=quad*8+j]; B[k=quad*8+j][n=lane&15]; D row=quad*4+reg.
template <int K, int BN, typename SRC>
__global__ __launch_bounds__(256) void mfma_gemm(const SRC* __restrict__ X,
                                                 const _Float16* __restrict__ Wt,
                                                 _Float16* __restrict__ H, int N) {
    constexpr int NT = BN / 16;
    const int wave = threadIdx.x >> 6;
    const int lane = threadIdx.x & 63;
    const int slab = blockIdx.x * 4 + wave;
    if (slab * 16 >= N) return;
    const int quad = lane >> 4;
    const int m = lane & 15;
    const int row = min(slab * 16 + m, N - 1);

    floatx4 acc[NT];
#pragma unroll
    for (int c = 0; c < NT; ++c) acc[c] = (floatx4){0.f, 0.f, 0.f, 0.f};

    for (int k0 = 0; k0 < K; k0 += 32) {
        half8 a;
        if constexpr (sizeof(SRC) == 4) {
            const float* xp = (const float*)&X[(size_t)row * K + k0 + quad * 8];
            float4 f0 = *(const float4*)xp;
            float4 f1 = *(const float4*)(xp + 4);
            a[0] = (_Float16)f0.x; a[1] = (_Float16)f0.y;
            a[2] = (_Float16)f0.z; a[3] = (_Float16)f0.w;
            a[4] = (_Float16)f1.x; a[5] = (_Float16)f1.y;
            a[6] = (_Float16)f1.z; a[7] = (_Float16)f1.w;
        } else {
            a = *(const half8*)&X[(size_t)row * K + k0 + quad * 8];
        }
#pragma unroll
        for (int c = 0; c < NT; ++c) {
            half8 b = *(const half8*)&Wt[(size_t)(c * 16 + m) * K + k0 + quad * 8];
            acc[c] = __builtin_amdgcn_mfma_f32_16x16x32_f16(a, b, acc[c], 0, 0, 0);
        }
    }

    const int r0 = slab * 16 + quad * 4;
#pragma unroll
    for (int c = 0; c < NT; ++c)
#pragma unroll
        for (int r = 0; r < 4; ++r)
            if (r0 + r < N)
                H[(size_t)(r0 + r) * BN + c * 16 + m] = (_Float16)acc[c][r];
}

// -------------------------------------------- fused aggregate + epilogue ----
// out[c][:] = relu( sum nrm*H[src] + dinv[c]^2*H[c] + b ).  H fp16,
// D/8 lanes per node (16B loads), fp32 accumulation. OUT = fp16 or fp32.
template <int D, typename OUT>
__global__ __launch_bounds__(256) void agg_kernel(const _Float16* __restrict__ H,
                                                  const int* __restrict__ row_ptr,
                                                  const int2* __restrict__ pairs,
                                                  const float* __restrict__ dinv,
                                                  const float* __restrict__ bias,
                                                  OUT* __restrict__ out, int N) {
    constexpr int TPN = D / 8;        // threads per node (8 halves = 16B each)
    constexpr int NPB = 256 / TPN;    // nodes per block
    const int tid = threadIdx.x;
    const int g = tid / TPN;
    const int lane = tid % TPN;
    const int node = blockIdx.x * NPB + g;
    if (node >= N) return;

    const int beg = row_ptr[node];
    const int end = row_ptr[node + 1];
    float acc[8];
#pragma unroll
    for (int j = 0; j < 8; ++j) acc[j] = 0.0f;

    for (int k = beg; k < end; ++k) {
        int2 p = pairs[k];
        float w = __int_as_float(p.y);
        half8 u = *(const half8*)&H[(size_t)p.x * D + lane * 8];
#pragma unroll
        for (int j = 0; j < 8; ++j) acc[j] = fmaf(w, (float)u[j], acc[j]);
    }
    // self-loop + bias + relu
    float di = dinv[node];
    float d2 = di * di;
    {
        half8 u = *(const half8*)&H[(size_t)node * D + lane * 8];
#pragma unroll
        for (int j = 0; j < 8; ++j) acc[j] = fmaf(d2, (float)u[j], acc[j]);
    }
    float b[8];
    *(float4*)&b[0] = *(const float4*)&bias[lane * 8];
    *(float4*)&b[4] = *(const float4*)&bias[lane * 8 + 4];
#pragma unroll
    for (int j = 0; j < 8; ++j) acc[j] = fmaxf(acc[j] + b[j], 0.f);

    if constexpr (sizeof(OUT) == 2) {
        half8 o;
#pragma unroll
        for (int j = 0; j < 8; ++j) o[j] = (_Float16)acc[j];
        *(half8*)&out[(size_t)node * D + lane * 8] = o;
    } else {
        float* dst = (float*)&out[(size_t)node * D + lane * 8];
        *(float4*)&dst[0] = make_float4(acc[0], acc[1], acc[2], acc[3]);
        *(float4*)&dst[4] = make_float4(acc[4], acc[5], acc[6], acc[7]);
    }
}

// ---------------------------------------------------------------- launch ----
extern "C" void kernel_launch(void* const* d_in, const int* in_sizes, int n_in,
                              void* d_out, int out_size, void* d_ws, size_t ws_size,
                              hipStream_t stream) {
    const float* x   = (const float*)d_in[0];
    const int* ei    = (const int*)d_in[1];
    const float* ew  = (const float*)d_in[2];
    const float* W1  = (const float*)d_in[3];
    const float* b1  = (const float*)d_in[4];
    const float* W2  = (const float*)d_in[5];
    const float* b2  = (const float*)d_in[6];
    const float* W3  = (const float*)d_in[7];
    const float* b3  = (const float*)d_in[8];
    float* out = (float*)d_out;

    const int N = in_sizes[0] / D0;   // 50000
    const int E = in_sizes[2];        // 800000
    (void)n_in; (void)out_size; (void)ws_size;

    // ---- workspace carving ----
    char* ws = (char*)d_ws;
    size_t off = 0;
    auto carve = [&](size_t bytes) -> void* {
        void* p = (void*)(ws + off);
        off += (bytes + 255) & ~(size_t)255;
        return p;
    };
    unsigned long long* pk = (unsigned long long*)carve((size_t)N * 8);
    float* dinv    = (float*)carve((size_t)N * 4);
    int*   cnt     = (int*)carve((size_t)N * 4);
    int*   row_ptr = (int*)carve((size_t)(N + 1) * 4);
    int*   cursor  = (int*)carve((size_t)N * 4);
    int*   bsum    = (int*)carve(256 * 4);
    int*   boff    = (int*)carve(256 * 4);
    int2*  pairs   = (int2*)carve((size_t)E * 8);
    _Float16* Wt1  = (_Float16*)carve((size_t)D0 * D1 * 2);
    _Float16* Wt2  = (_Float16*)carve((size_t)D1 * D2 * 2);
    _Float16* Wt3  = (_Float16*)carve((size_t)D2 * D3 * 2);
    _Float16* bufH = (_Float16*)carve((size_t)N * D1 * 2);  // h1/h2/h3
    _Float16* bufO = (_Float16*)carve((size_t)N * D1 * 2);  // out1/out2 (fp16)

    _Float16* h1   = bufH;               // N x 128 fp16
    _Float16* out1 = bufO;               // N x 128 fp16 ; x for layer 2
    _Float16* h2   = bufH;               // N x 64 fp16 (h1 dead)
    _Float16* out2 = bufO;               // N x 64 fp16 (out1 dead after gemm2)
    _Float16* h3   = bufH;               // N x 32 fp16 (h2 dead)

    const int eb = (E + 255) / 256;
    const int scanB = (N + 255) / 256;   // must be <= 256
    const int slabs = (N + 15) / 16;
    const int gemmB = (slabs + 3) / 4;

    // ---- weight transpose+convert (independent of CSR build) ----
    wcvt_kernel<D0, D1><<<(D0 * D1 + 255) / 256, 256, 0, stream>>>(W1, Wt1);
    wcvt_kernel<D1, D2><<<(D1 * D2 + 255) / 256, 256, 0, stream>>>(W2, Wt2);
    wcvt_kernel<D2, D3><<<(D2 * D3 + 255) / 256, 256, 0, stream>>>(W3, Wt3);

    // ---- CSR build + normalization ----
    hipMemsetAsync(pk, 0, (size_t)N * 8, stream);
    deg_hist_kernel<<<eb, 256, 0, stream>>>(ei, ew, pk, E);
    scan_reduce<<<scanB, 256, 0, stream>>>(pk, dinv, cnt, bsum, N);
    scan_blocksums<<<1, 256, 0, stream>>>(bsum, boff, &row_ptr[N], scanB);
    scan_apply<<<scanB, 256, 0, stream>>>(cnt, boff, row_ptr, cursor, N);
    fill_kernel<<<eb, 256, 0, stream>>>(ei, ew, dinv, cursor, pairs, E);

    // ---- layer 1: 256 -> 128 ----
    mfma_gemm<D0, D1, float><<<gemmB, 256, 0, stream>>>(x, Wt1, h1, N);
    agg_kernel<D1, _Float16><<<(N + 15) / 16, 256, 0, stream>>>(h1, row_ptr, pairs, dinv, b1, out1, N);

    // ---- layer 2: 128 -> 64 ----
    mfma_gemm<D1, D2, _Float16><<<gemmB, 256, 0, stream>>>(out1, Wt2, h2, N);
    agg_kernel<D2, _Float16><<<(N + 31) / 32, 256, 0, stream>>>(h2, row_ptr, pairs, dinv, b2, out2, N);

    // ---- layer 3: 64 -> 32 ----
    mfma_gemm<D2, D3, _Float16><<<gemmB, 256, 0, stream>>>(out2, Wt3, h3, N);
    agg_kernel<D3, float><<<(N + 63) / 64, 256, 0, stream>>>(h3, row_ptr, pairs, dinv, b3, out, N);
}

// Round 8
// 307.574 us; speedup vs baseline: 2.8407x; 1.0729x over previous
//
#include <hip/hip_runtime.h>
#include <hip/hip_fp16.h>

// GCN encoder: 3x (GCNConv + ReLU), dims 256->128->64->32
// N=50000 nodes, E=800000 edges. edge_index delivered as int32 (harness).
// R2: CSR gather instead of atomic scatter.
// R3: multi-block 3-phase scan.
// R4: packed 64-bit deg+cnt atomic, int2 CSR payload.
// R5: fp16 H gather buffer, dinv fused into scan.
// R6: MFMA fp16 GEMMs (LDS-free, per-wave 16-row slabs), fp16 activations.
// R7: rank from deg_hist's atomic return value -> atomic-free fill
//     (removes the 25.6MB cursor write-through stream).

#define D0 256
#define D1 128
#define D2 64
#define D3 32

#define FIX_SCALE 16777216.0f           // 2^24 fixed-point for degree
#define FIX_INV   (1.0f / 16777216.0f)

typedef _Float16 half8 __attribute__((ext_vector_type(8)));
typedef float floatx4 __attribute__((ext_vector_type(4)));

// ------------------------------------------------- degree + histogram ------
// Packed atomic: high 32 = count, low 32 = fixed-point weighted degree.
// The returned old value's high word is this edge's rank within its dest.
__global__ void deg_hist_kernel(const int* __restrict__ ei, const float* __restrict__ ew,
                                unsigned long long* __restrict__ pk,
                                int* __restrict__ rank, int E) {
    int e = blockIdx.x * blockDim.x + threadIdx.x;
    if (e < E) {
        int c = ei[E + e];   // col (target)
        unsigned int wfix = (unsigned int)(ew[e] * FIX_SCALE + 0.5f);
        unsigned long long old = atomicAdd(&pk[c], (1ULL << 32) | (unsigned long long)wfix);
        rank[e] = (int)(old >> 32);
    }
}

// --------------------------------------------- 3-phase exclusive scan ------
__global__ __launch_bounds__(256) void scan_reduce(const unsigned long long* __restrict__ pk,
                                                   float* __restrict__ dinv,
                                                   int* __restrict__ cnt,
                                                   int* __restrict__ blockSum, int N) {
    __shared__ int s[256];
    const int t = threadIdx.x;
    const int i = blockIdx.x * 256 + t;
    int v = 0;
    if (i < N) {
        unsigned long long p = pk[i];
        float d = (float)(unsigned int)(p & 0xffffffffULL) * FIX_INV + 1.0f;  // +1 self-loop
        dinv[i] = rsqrtf(d);
        v = (int)(p >> 32);
        cnt[i] = v;
    }
    s[t] = v;
    __syncthreads();
#pragma unroll
    for (int off = 128; off > 0; off >>= 1) {
        if (t < off) s[t] += s[t + off];
        __syncthreads();
    }
    if (t == 0) blockSum[blockIdx.x] = s[0];
}

__global__ __launch_bounds__(256) void scan_blocksums(int* __restrict__ blockSum,
                                                      int* __restrict__ blockOff,
                                                      int* __restrict__ row_ptr_N,
                                                      int B) {
    __shared__ int s[256];
    const int t = threadIdx.x;
    const int v = (t < B) ? blockSum[t] : 0;
    s[t] = v;
    __syncthreads();
#pragma unroll
    for (int off = 1; off < 256; off <<= 1) {
        int u = (t >= off) ? s[t - off] : 0;
        __syncthreads();
        s[t] += u;
        __syncthreads();
    }
    if (t < B) blockOff[t] = s[t] - v;
    if (t == 255) *row_ptr_N = s[255];
}

__global__ __launch_bounds__(256) void scan_apply(const int* __restrict__ cnt,
                                                  const int* __restrict__ blockOff,
                                                  int* __restrict__ row_ptr, int N) {
    __shared__ int s[256];
    const int t = threadIdx.x;
    const int i = blockIdx.x * 256 + t;
    const int v = (i < N) ? cnt[i] : 0;
    s[t] = v;
    __syncthreads();
#pragma unroll
    for (int off = 1; off < 256; off <<= 1) {
        int u = (t >= off) ? s[t - off] : 0;
        __syncthreads();
        s[t] += u;
        __syncthreads();
    }
    if (i < N) row_ptr[i] = s[t] - v + blockOff[blockIdx.x];
}

// ------------------------------------------------- bucket fill (CSR) -------
// Atomic-free: position = row_ptr[c] + rank[e].
__global__ void fill_kernel(const int* __restrict__ ei, const float* __restrict__ ew,
                            const float* __restrict__ dinv,
                            const int* __restrict__ row_ptr, const int* __restrict__ rank,
                            int2* __restrict__ pairs, int E) {
    int e = blockIdx.x * blockDim.x + threadIdx.x;
    if (e < E) {
        int r = ei[e];
        int c = ei[E + e];
        float w = dinv[r] * ew[e] * dinv[c];
        pairs[row_ptr[c] + rank[e]] = make_int2(r, __float_as_int(w));
    }
}

// ----------------------------------------------- W transpose+convert -------
template <int K, int DOUT>
__global__ void wcvt_kernel(const float* __restrict__ W, _Float16* __restrict__ Wt) {
    int idx = blockIdx.x * 256 + threadIdx.x;
    if (idx < K * DOUT) {
        int k = idx / DOUT, n = idx % DOUT;
        Wt[n * K + k] = (_Float16)W[idx];
    }
}

// ----------------------------------------------------------- MFMA GEMM -----
// H[N,BN] (fp16) = X[N,K] @ Wt^T, Wt is [BN][K] fp16. One wave per 16-row
// slab. A[m=lane&15][k=quad*8+j]; B[k][n=lane&15]; D row=quad*4+reg.
template <int K, int BN, typename SRC>
__global__ __launch_bounds__(256) void mfma_gemm(const SRC* __restrict__ X,
                                                 const _Float16* __restrict__ Wt,
                                                 _Float16* __restrict__ H, int N) {
    constexpr int NT = BN / 16;
    const int wave = threadIdx.x >> 6;
    const int lane = threadIdx.x & 63;
    const int slab = blockIdx.x * 4 + wave;
    if (slab * 16 >= N) return;
    const int quad = lane >> 4;
    const int m = lane & 15;
    const int row = min(slab * 16 + m, N - 1);

    floatx4 acc[NT];
#pragma unroll
    for (int c = 0; c < NT; ++c) acc[c] = (floatx4){0.f, 0.f, 0.f, 0.f};

    for (int k0 = 0; k0 < K; k0 += 32) {
        half8 a;
        if constexpr (sizeof(SRC) == 4) {
            const float* xp = (const float*)&X[(size_t)row * K + k0 + quad * 8];
            float4 f0 = *(const float4*)xp;
            float4 f1 = *(const float4*)(xp + 4);
            a[0] = (_Float16)f0.x; a[1] = (_Float16)f0.y;
            a[2] = (_Float16)f0.z; a[3] = (_Float16)f0.w;
            a[4] = (_Float16)f1.x; a[5] = (_Float16)f1.y;
            a[6] = (_Float16)f1.z; a[7] = (_Float16)f1.w;
        } else {
            a = *(const half8*)&X[(size_t)row * K + k0 + quad * 8];
        }
#pragma unroll
        for (int c = 0; c < NT; ++c) {
            half8 b = *(const half8*)&Wt[(size_t)(c * 16 + m) * K + k0 + quad * 8];
            acc[c] = __builtin_amdgcn_mfma_f32_16x16x32_f16(a, b, acc[c], 0, 0, 0);
        }
    }

    const int r0 = slab * 16 + quad * 4;
#pragma unroll
    for (int c = 0; c < NT; ++c)
#pragma unroll
        for (int r = 0; r < 4; ++r)
            if (r0 + r < N)
                H[(size_t)(r0 + r) * BN + c * 16 + m] = (_Float16)acc[c][r];
}

// -------------------------------------------- fused aggregate + epilogue ----
template <int D, typename OUT>
__global__ __launch_bounds__(256) void agg_kernel(const _Float16* __restrict__ H,
                                                  const int* __restrict__ row_ptr,
                                                  const int2* __restrict__ pairs,
                                                  const float* __restrict__ dinv,
                                                  const float* __restrict__ bias,
                                                  OUT* __restrict__ out, int N) {
    constexpr int TPN = D / 8;        // threads per node (8 halves = 16B each)
    constexpr int NPB = 256 / TPN;    // nodes per block
    const int tid = threadIdx.x;
    const int g = tid / TPN;
    const int lane = tid % TPN;
    const int node = blockIdx.x * NPB + g;
    if (node >= N) return;

    const int beg = row_ptr[node];
    const int end = row_ptr[node + 1];
    float acc[8];
#pragma unroll
    for (int j = 0; j < 8; ++j) acc[j] = 0.0f;

    for (int k = beg; k < end; ++k) {
        int2 p = pairs[k];
        float w = __int_as_float(p.y);
        half8 u = *(const half8*)&H[(size_t)p.x * D + lane * 8];
#pragma unroll
        for (int j = 0; j < 8; ++j) acc[j] = fmaf(w, (float)u[j], acc[j]);
    }
    // self-loop + bias + relu
    float di = dinv[node];
    float d2 = di * di;
    {
        half8 u = *(const half8*)&H[(size_t)node * D + lane * 8];
#pragma unroll
        for (int j = 0; j < 8; ++j) acc[j] = fmaf(d2, (float)u[j], acc[j]);
    }
    float b[8];
    *(float4*)&b[0] = *(const float4*)&bias[lane * 8];
    *(float4*)&b[4] = *(const float4*)&bias[lane * 8 + 4];
#pragma unroll
    for (int j = 0; j < 8; ++j) acc[j] = fmaxf(acc[j] + b[j], 0.f);

    if constexpr (sizeof(OUT) == 2) {
        half8 o;
#pragma unroll
        for (int j = 0; j < 8; ++j) o[j] = (_Float16)acc[j];
        *(half8*)&out[(size_t)node * D + lane * 8] = o;
    } else {
        float* dst = (float*)&out[(size_t)node * D + lane * 8];
        *(float4*)&dst[0] = make_float4(acc[0], acc[1], acc[2], acc[3]);
        *(float4*)&dst[4] = make_float4(acc[4], acc[5], acc[6], acc[7]);
    }
}

// ---------------------------------------------------------------- launch ----
extern "C" void kernel_launch(void* const* d_in, const int* in_sizes, int n_in,
                              void* d_out, int out_size, void* d_ws, size_t ws_size,
                              hipStream_t stream) {
    const float* x   = (const float*)d_in[0];
    const int* ei    = (const int*)d_in[1];
    const float* ew  = (const float*)d_in[2];
    const float* W1  = (const float*)d_in[3];
    const float* b1  = (const float*)d_in[4];
    const float* W2  = (const float*)d_in[5];
    const float* b2  = (const float*)d_in[6];
    const float* W3  = (const float*)d_in[7];
    const float* b3  = (const float*)d_in[8];
    float* out = (float*)d_out;

    const int N = in_sizes[0] / D0;   // 50000
    const int E = in_sizes[2];        // 800000
    (void)n_in; (void)out_size; (void)ws_size;

    // ---- workspace carving ----
    char* ws = (char*)d_ws;
    size_t off = 0;
    auto carve = [&](size_t bytes) -> void* {
        void* p = (void*)(ws + off);
        off += (bytes + 255) & ~(size_t)255;
        return p;
    };
    unsigned long long* pk = (unsigned long long*)carve((size_t)N * 8);
    float* dinv    = (float*)carve((size_t)N * 4);
    int*   cnt     = (int*)carve((size_t)N * 4);
    int*   row_ptr = (int*)carve((size_t)(N + 1) * 4);
    int*   rank    = (int*)carve((size_t)E * 4);
    int*   bsum    = (int*)carve(256 * 4);
    int*   boff    = (int*)carve(256 * 4);
    int2*  pairs   = (int2*)carve((size_t)E * 8);
    _Float16* Wt1  = (_Float16*)carve((size_t)D0 * D1 * 2);
    _Float16* Wt2  = (_Float16*)carve((size_t)D1 * D2 * 2);
    _Float16* Wt3  = (_Float16*)carve((size_t)D2 * D3 * 2);
    _Float16* bufH = (_Float16*)carve((size_t)N * D1 * 2);  // h1/h2/h3
    _Float16* bufO = (_Float16*)carve((size_t)N * D1 * 2);  // out1/out2 (fp16)

    _Float16* h1   = bufH;               // N x 128 fp16
    _Float16* out1 = bufO;               // N x 128 fp16 ; x for layer 2
    _Float16* h2   = bufH;               // N x 64 fp16 (h1 dead)
    _Float16* out2 = bufO;               // N x 64 fp16 (out1 dead after gemm2)
    _Float16* h3   = bufH;               // N x 32 fp16 (h2 dead)

    const int eb = (E + 255) / 256;
    const int scanB = (N + 255) / 256;   // must be <= 256
    const int slabs = (N + 15) / 16;
    const int gemmB = (slabs + 3) / 4;

    // ---- weight transpose+convert (independent of CSR build) ----
    wcvt_kernel<D0, D1><<<(D0 * D1 + 255) / 256, 256, 0, stream>>>(W1, Wt1);
    wcvt_kernel<D1, D2><<<(D1 * D2 + 255) / 256, 256, 0, stream>>>(W2, Wt2);
    wcvt_kernel<D2, D3><<<(D2 * D3 + 255) / 256, 256, 0, stream>>>(W3, Wt3);

    // ---- CSR build + normalization ----
    hipMemsetAsync(pk, 0, (size_t)N * 8, stream);
    deg_hist_kernel<<<eb, 256, 0, stream>>>(ei, ew, pk, rank, E);
    scan_reduce<<<scanB, 256, 0, stream>>>(pk, dinv, cnt, bsum, N);
    scan_blocksums<<<1, 256, 0, stream>>>(bsum, boff, &row_ptr[N], scanB);
    scan_apply<<<scanB, 256, 0, stream>>>(cnt, boff, row_ptr, N);
    fill_kernel<<<eb, 256, 0, stream>>>(ei, ew, dinv, row_ptr, rank, pairs, E);

    // ---- layer 1: 256 -> 128 ----
    mfma_gemm<D0, D1, float><<<gemmB, 256, 0, stream>>>(x, Wt1, h1, N);
    agg_kernel<D1, _Float16><<<(N + 15) / 16, 256, 0, stream>>>(h1, row_ptr, pairs, dinv, b1, out1, N);

    // ---- layer 2: 128 -> 64 ----
    mfma_gemm<D1, D2, _Float16><<<gemmB, 256, 0, stream>>>(out1, Wt2, h2, N);
    agg_kernel<D2, _Float16><<<(N + 31) / 32, 256, 0, stream>>>(h2, row_ptr, pairs, dinv, b2, out2, N);

    // ---- layer 3: 64 -> 32 ----
    mfma_gemm<D2, D3, _Float16><<<gemmB, 256, 0, stream>>>(out2, Wt3, h3, N);
    agg_kernel<D3, float><<<(N + 63) / 64, 256, 0, stream>>>(h3, row_ptr, pairs, dinv, b3, out, N);
}